// Round 6
// baseline (108.274 us; speedup 1.0000x reference)
//
#include <hip/hip_runtime.h>

#define NN 4
#define CIN 256
#define CH 128       // gconv out channels = AC = oconv channels
#define HH 64
#define hh 32
#define L 1024
#define NB 2048      // CH*16
#define PENALTY -10000.0f
#define EPS 1e-4f

typedef __bf16 bf16x8 __attribute__((ext_vector_type(8)));
typedef float f32x4 __attribute__((ext_vector_type(4)));
typedef __attribute__((address_space(3))) void lds_t;
typedef __attribute__((address_space(1))) const void gbl_t;

__device__ __forceinline__ int refl32(int t) { return t < 0 ? -t : (t > 31 ? 62 - t : t); }
__device__ __forceinline__ int refl64(int t) { return t < 0 ? -t : (t > 63 ? 126 - t : t); }
// XOR-swizzle of element index (16B/8-elem granule) within a 32-elem K-chunk, keyed by row
__device__ __forceinline__ int swz(int k, int row) { return k ^ (((row >> 1) & 3) << 3); }

// ---- fused prep: alpha->Bt patches (blocks 0..511), img downsample+transpose
// ---- (512..639), unknown stats (640..643), weight convert + stats/flag-zero (644..679) ----
__global__ void k_prep(const float* __restrict__ img, const float* __restrict__ gw,
                       const float* __restrict__ ow, const float* __restrict__ unknown,
                       const float* __restrict__ alpha,
                       __bf16* __restrict__ Xb, __bf16* __restrict__ gwb,
                       __bf16* __restrict__ owb, float* __restrict__ unk,
                       float* __restrict__ scales, __bf16* __restrict__ Bt,
                       float* __restrict__ stats) {
    __shared__ float sm[CIN * 33];
    int bid = blockIdx.x, t = threadIdx.x;
    if (bid < 512) {
        // btbuild: one block per (n,o): stage alpha plane (coalesced), emit 16 ab rows.
        int n = bid >> 7, o = bid & 127;
        const float* ap = alpha + ((size_t)(n * CH + o) << 12);
#pragma unroll
        for (int j = 0; j < 4; ++j) {
            int fi = t + j * 256;      // float4 index 0..1023
            int row = fi >> 4, c4 = fi & 15;
            float4 v = *(const float4*)(ap + fi * 4);
            float* d = sm + row * 65 + c4 * 4;
            d[0] = v.x; d[1] = v.y; d[2] = v.z; d[3] = v.w;
        }
        __syncthreads();
        __bf16* Bn = Bt + ((size_t)(n * NB) << 10);
#pragma unroll
        for (int gi = 0; gi < 8; ++gi) {
            int g = gi * 256 + t;      // granule 0..2047
            int ab = g >> 7, qg = g & 127;
            int a = ab >> 2, bb = ab & 3;
            int q0 = qg * 8;
            int qi = q0 >> 5, qj0 = q0 & 31;
            int ti = refl64(2 * qi + a - 1);
            const float* r = sm + ti * 65;
            __bf16 v[8];
#pragma unroll
            for (int s = 0; s < 8; ++s) v[s] = (__bf16)r[refl64(2 * (qj0 + s) + bb - 1)];
            int j = ab * 128 + o;
            *(bf16x8*)(Bn + ((size_t)j << 10) + swz(q0, j)) = *(bf16x8*)v;
        }
    } else if (bid < 640) {
        // prep_x: downsample img (vectorized: float4 -> keep .x/.z), transpose to [np][c]
        int idx = bid - 512;
        int i = idx & 31, n = idx >> 5;
        for (int e = t; e < CIN * 16; e += 256) {
            int c = e >> 4, j2 = e & 15;
            float4 v = *(const float4*)(img + (((size_t)n * CIN + c) * HH + 2 * i) * HH + 4 * j2);
            sm[c * 33 + 2 * j2] = v.x;
            sm[c * 33 + 2 * j2 + 1] = v.z;
        }
        __syncthreads();
#pragma unroll
        for (int j = 0; j < 32; ++j) {
            int np = (n << 10) + i * 32 + j;
            int cl = swz(t, np);
            Xb[(size_t)np * CIN + t] = (__bf16)sm[cl * 33 + j];
        }
    } else if (bid < 644) {
        // stats: unknown downsample, mean -> scales, 3x3 reflect box mean -> unk
        int n = bid - 640;
        float* u = sm;            // [1024]
        float* red = sm + 1024;   // [256]
        float part = 0.f;
#pragma unroll
        for (int c = 0; c < 4; ++c) {
            int idx = t + c * 256;
            int i = idx >> 5, j = idx & 31;
            float v = unknown[n * 4096 + (2 * i) * HH + 2 * j];
            u[idx] = v;
            part += v;
        }
        red[t] = part;
        __syncthreads();
        for (int s = 128; s > 0; s >>= 1) {
            if (t < s) red[t] += red[t + s];
            __syncthreads();
        }
        if (t == 0) {
            float um = red[0] / 1024.0f;
            float km = 1.0f - um;
            scales[n * 2] = fminf(fmaxf(sqrtf(um / km), 0.1f), 10.0f);
            scales[n * 2 + 1] = fminf(fmaxf(sqrtf(km / um), 0.1f), 10.0f);
        }
#pragma unroll
        for (int c = 0; c < 4; ++c) {
            int idx = t + c * 256;
            int i = idx >> 5, j = idx & 31;
            float sum = 0.f;
#pragma unroll
            for (int di = -1; di <= 1; ++di)
#pragma unroll
                for (int dj = -1; dj <= 1; ++dj)
                    sum += u[refl32(i + di) * 32 + refl32(j + dj)];
            unk[n * L + idx] = sum * (1.0f / 9.0f);
        }
    } else {
        // prep_w: weights -> bf16 pre-swizzled; block 644 zeros BN stats + done-flag
        if (bid == 644) {
            stats[t] = 0.f;
            if (t == 0) *(unsigned*)(scales + 56) = 0u;
        }
        for (int e = (bid - 644) * 256 + t; e < 49152; e += 36 * 256) {
            if (e < 32768) {
                int o = e >> 8, m = e & 255;
                gwb[e] = (__bf16)gw[o * 256 + swz(m, o)];
            } else {
                int e2 = e - 32768;
                int j = e2 >> 7, m = e2 & 127;
                owb[e2] = (__bf16)ow[j * 128 + swz(m, j)];
            }
        }
    }
}

// ---- MFMA GEMM0: gbf[np][o] = Xb . gwb^T + gb, bf16 out ----
__global__ __launch_bounds__(256, 2) void k_gemm0(const __bf16* __restrict__ Xb,
                                                  const __bf16* __restrict__ gwb,
                                                  const float* __restrict__ gb,
                                                  __bf16* __restrict__ gbf) {
    __shared__ __align__(16) __bf16 As[128 * 32];
    __shared__ __align__(16) __bf16 Bs[128 * 32];
    int p0 = blockIdx.x * 128;
    int t = threadIdx.x, l = t & 63, w = t >> 6;
    int wr = w >> 1, wc = w & 1;
    f32x4 acc[4][4] = {};
    for (int k0 = 0; k0 < CIN; k0 += 32) {
#pragma unroll
        for (int i = 0; i < 2; ++i) {
            const __bf16* srcA = Xb + (size_t)(p0 + i * 64 + (t >> 2)) * CIN + k0 + (t & 3) * 8;
            __builtin_amdgcn_global_load_lds((gbl_t*)srcA, (lds_t*)(As + i * 2048 + t * 8), 16, 0, 0);
            const __bf16* srcB = gwb + (size_t)(i * 64 + (t >> 2)) * CIN + k0 + (t & 3) * 8;
            __builtin_amdgcn_global_load_lds((gbl_t*)srcB, (lds_t*)(Bs + i * 2048 + t * 8), 16, 0, 0);
        }
        __syncthreads();
        int gl = l >> 4, r = l & 15;
        bf16x8 av[4], bv[4];
#pragma unroll
        for (int m = 0; m < 4; ++m) {
            int row = wr * 64 + m * 16 + r;
            av[m] = *(const bf16x8*)(As + row * 32 + swz(gl << 3, row));
            int col = wc * 64 + m * 16 + r;
            bv[m] = *(const bf16x8*)(Bs + col * 32 + swz(gl << 3, col));
        }
#pragma unroll
        for (int m = 0; m < 4; ++m)
#pragma unroll
            for (int c2 = 0; c2 < 4; ++c2)
                acc[m][c2] = __builtin_amdgcn_mfma_f32_16x16x32_bf16(av[m], bv[c2], acc[m][c2], 0, 0, 0);
        __syncthreads();
    }
    int r = l & 15, hi = l >> 4;
#pragma unroll
    for (int m = 0; m < 4; ++m)
#pragma unroll
        for (int c2 = 0; c2 < 4; ++c2) {
            int o = wc * 64 + c2 * 16 + r;
            float bias = gb[o];
#pragma unroll
            for (int reg = 0; reg < 4; ++reg) {
                int row = p0 + wr * 64 + m * 16 + hi * 4 + reg;
                gbf[((size_t)row << 7) + o] = (__bf16)(acc[m][c2][reg] + bias);
            }
        }
}

// ---- MFMA GEMM1 + fused ssq/normf: A window (48 KB) resident, B window in 2
// ---- halves (24 KB) -> 75 KB LDS total -> 2 blocks/CU. f computed from B window. ----
__global__ __launch_bounds__(256, 2) void k_gemm1(const __bf16* __restrict__ gbf,
                                                  const float* __restrict__ unk,
                                                  const float* __restrict__ scales,
                                                  float* __restrict__ W) {
    __shared__ __align__(16) unsigned char RAW[75008];
    __bf16* As1 = (__bf16*)RAW;            // [4][192][32]
    __bf16* Bh = (__bf16*)(RAW + 49152);   // [2][192][32]
    float* ssq = (float*)(RAW + 73728);    // [192]
    float* ftile = ssq + 192;              // [128]
    int n = blockIdx.z;
    int p0 = blockIdx.y * 128, q0 = blockIdx.x * 128;
    const __bf16* gn = gbf + ((size_t)n << 17);
    int t = threadIdx.x, l = t & 63, w = t >> 6;
    int wr = w >> 1, wc = w & 1;
    int by4 = blockIdx.y * 4, bx4 = blockIdx.x * 4;
    int rbA = by4 - 1; rbA = rbA < 0 ? 0 : (rbA > 26 ? 26 : rbA);
    int rbB = bx4 - 1; rbB = rbB < 0 ? 0 : (rbB > 26 ? 26 : rbB);
#pragma unroll
    for (int k = 0; k < 12; ++k) {  // stage full A window
        int chunk = k / 3;
        int rem = (k % 3) * 256 + t;
        int wrow = rem >> 2, sg = rem & 3;
        int so = (chunk << 5) + ((sg ^ ((wrow >> 1) & 3)) << 3);
        int grA = ((rbA + (wrow >> 5)) << 5) + (wrow & 31);
        __builtin_amdgcn_global_load_lds((gbl_t*)(gn + (size_t)grA * 128 + so),
                                         (lds_t*)(As1 + chunk * 6144 + rem * 8), 16, 0, 0);
    }
    auto stageB = [&](int h) {
#pragma unroll
        for (int k = 0; k < 6; ++k) {
            int cl = k / 3;
            int cc = 2 * h + cl;
            int rem = (k % 3) * 256 + t;
            int wrow = rem >> 2, sg = rem & 3;
            int so = (cc << 5) + ((sg ^ ((wrow >> 1) & 3)) << 3);
            int grB = ((rbB + (wrow >> 5)) << 5) + (wrow & 31);
            __builtin_amdgcn_global_load_lds((gbl_t*)(gn + (size_t)grB * 128 + so),
                                             (lds_t*)(Bh + cl * 6144 + rem * 8), 16, 0, 0);
        }
    };
    stageB(0);
    int gl = l >> 4, r = l & 15;
    int rpA_[4][3], cpA_[4][3], rpB_[4][3], cpB_[4][3];
#pragma unroll
    for (int m = 0; m < 4; ++m) {
        int prow = wr * 64 + m * 16 + r;
        int qrow = wc * 64 + m * 16 + r;
#pragma unroll
        for (int d = 0; d < 3; ++d) {
            rpA_[m][d] = (refl32(by4 + (prow >> 5) + d - 1) - rbA) << 10;
            int cp = refl32((prow & 31) + d - 1);
            cpA_[m][d] = cp * 32 + ((gl ^ ((cp >> 1) & 3)) << 3);
            rpB_[m][d] = (refl32(bx4 + (qrow >> 5) + d - 1) - rbB) << 10;
            int cq = refl32((qrow & 31) + d - 1);
            cpB_[m][d] = cq * 32 + ((gl ^ ((cq >> 1) & 3)) << 3);
        }
    }
    f32x4 acc[4][4] = {};
    float ssqAcc = 0.f;
    auto computeH = [&](int h) {
        __builtin_amdgcn_s_setprio(1);
#pragma unroll
        for (int dk = 0; dk < 3; ++dk)
#pragma unroll
            for (int dl = 0; dl < 3; ++dl)
#pragma unroll
                for (int c = 0; c < 2; ++c) {
                    int cc = 2 * h + c;
                    bf16x8 av[4], bv[4];
#pragma unroll
                    for (int m = 0; m < 4; ++m) {
                        av[m] = *(const bf16x8*)(As1 + cc * 6144 + rpA_[m][dk] + cpA_[m][dl]);
                        bv[m] = *(const bf16x8*)(Bh + c * 6144 + rpB_[m][dk] + cpB_[m][dl]);
                    }
#pragma unroll
                    for (int m = 0; m < 4; ++m)
#pragma unroll
                        for (int c2 = 0; c2 < 4; ++c2)
                            acc[m][c2] = __builtin_amdgcn_mfma_f32_16x16x32_bf16(av[m], bv[c2], acc[m][c2], 0, 0, 0);
                }
        __builtin_amdgcn_s_setprio(0);
        // ssq partial from this B half (ch [h*64, h*64+64) in linear order)
        if (t < 192) {
            int key = (t >> 1) & 3;
#pragma unroll
            for (int c = 0; c < 2; ++c)
#pragma unroll
                for (int g = 0; g < 4; ++g) {
                    bf16x8 v = *(const bf16x8*)(Bh + c * 6144 + t * 32 + ((g ^ key) << 3));
#pragma unroll
                    for (int u2 = 0; u2 < 8; ++u2) {
                        float x = (float)v[u2];
                        ssqAcc += x * x;
                    }
                }
        }
    };
    __syncthreads();
    computeH(0);
    __syncthreads();
    stageB(1);
    __syncthreads();
    computeH(1);
    if (t < 192) ssq[t] = ssqAcc;
    __syncthreads();
    if (t < 128) {
        int q = q0 + t;
        int qi = q >> 5, qj = q & 31;
        float sum = 0.f;
#pragma unroll
        for (int di = -1; di <= 1; ++di)
#pragma unroll
            for (int dj = -1; dj <= 1; ++dj)
                sum += ssq[(refl32(qi + di) - rbB) * 32 + refl32(qj + dj)];
        float sc = unk[n * L + q] > 0.f ? scales[n * 2] : scales[n * 2 + 1];
        ftile[t] = sc / fmaxf(sqrtf(sum), EPS);
    }
    __syncthreads();
    int hi = l >> 4;
#pragma unroll
    for (int m = 0; m < 4; ++m)
#pragma unroll
        for (int c2 = 0; c2 < 4; ++c2) {
            int q = q0 + wc * 64 + c2 * 16 + r;
            float fq = ftile[wc * 64 + c2 * 16 + r];
#pragma unroll
            for (int reg = 0; reg < 4; ++reg) {
                int p = p0 + wr * 64 + m * 16 + hi * 4 + reg;
                float val = acc[m][c2][reg] * fq;
                if (p == q) val += PENALTY * unk[n * L + p];
                W[((size_t)n << 20) + ((size_t)p << 10) + q] = val;
            }
        }
}

// ---- row softmax: one wave per row, shuffle-only; writes swizzled bf16 Wb ----
__global__ void k_softmax(const float* __restrict__ W, __bf16* __restrict__ Wb) {
    int t = threadIdx.x, wv = t >> 6, lane = t & 63;
    int row = blockIdx.x * 4 + wv;  // n*L + p
    const float* Wr = W + (size_t)row * 1024;
    float v[16];
    float mx = -1e30f;
#pragma unroll
    for (int k = 0; k < 16; ++k) {
        v[k] = Wr[lane + k * 64];
        mx = fmaxf(mx, v[k]);
    }
#pragma unroll
    for (int off = 32; off > 0; off >>= 1) mx = fmaxf(mx, __shfl_xor(mx, off));
    float sum = 0.f;
#pragma unroll
    for (int k = 0; k < 16; ++k) {
        v[k] = __expf(v[k] - mx);
        sum += v[k];
    }
#pragma unroll
    for (int off = 32; off > 0; off >>= 1) sum += __shfl_xor(sum, off);
    float inv = 1.0f / sum;
    int p = row & (L - 1);
    int key = ((p >> 1) & 3) << 3;
    __bf16* Wbr = Wb + (size_t)row * 1024;
#pragma unroll
    for (int k = 0; k < 16; ++k) {
        int idx = lane + k * 64;
        Wbr[idx ^ key] = (__bf16)(v[k] * inv);
    }
}

// ---- MFMA GEMM2: Tb[p][j] = sum_q W[p][q] * Bt[j][q].
// ---- 4-buffer BK=32 pipeline, counted vmcnt (T4): never drain to 0 mid-loop. ----
__global__ __launch_bounds__(256, 2) void k_gemm2(const __bf16* __restrict__ Wb,
                                                  const __bf16* __restrict__ Bt,
                                                  __bf16* __restrict__ Tb) {
    int bid = blockIdx.x;
    int xcd = bid & 7, idx = bid >> 3;
    int n = xcd >> 1;
    int p0 = ((xcd & 1) * 4 + (idx & 3)) * 128;
    int j0 = (idx >> 2) * 128;
    __shared__ __align__(16) __bf16 As[4][4096];  // [buf][128 rows][32]
    __shared__ __align__(16) __bf16 Bs[4][4096];
    const __bf16* An = Wb + ((size_t)n << 20);
    const __bf16* Bn = Bt + ((size_t)n * NB << 10);
    int t = threadIdx.x, l = t & 63, w = t >> 6;
    int wr = w >> 1, wc = w & 1;
    int gl = l >> 4, r = l & 15;
    f32x4 acc[4][4] = {};

    auto stage = [&](int buf, int k0) {
#pragma unroll
        for (int i = 0; i < 2; ++i) {
            int row = (t >> 2) + i * 64;
            int sgo = (t & 3) * 8;
            const __bf16* srcA = An + ((size_t)(p0 + row) << 10) + k0 + sgo;
            __builtin_amdgcn_global_load_lds((gbl_t*)srcA, (lds_t*)(&As[buf][row * 32 + sgo]), 16, 0, 0);
            const __bf16* srcB = Bn + ((size_t)(j0 + row) << 10) + k0 + sgo;
            __builtin_amdgcn_global_load_lds((gbl_t*)srcB, (lds_t*)(&Bs[buf][row * 32 + sgo]), 16, 0, 0);
        }
    };
    auto compute = [&](int buf) {
        bf16x8 av[4], bv[4];
#pragma unroll
        for (int m = 0; m < 4; ++m) {
            int row = wr * 64 + m * 16 + r;
            av[m] = *(const bf16x8*)(&As[buf][row * 32 + ((gl ^ ((row >> 1) & 3)) << 3)]);
            int col = wc * 64 + m * 16 + r;
            bv[m] = *(const bf16x8*)(&Bs[buf][col * 32 + ((gl ^ ((col >> 1) & 3)) << 3)]);
        }
#pragma unroll
        for (int m = 0; m < 4; ++m)
#pragma unroll
            for (int c2 = 0; c2 < 4; ++c2)
                acc[m][c2] = __builtin_amdgcn_mfma_f32_16x16x32_bf16(av[m], bv[c2], acc[m][c2], 0, 0, 0);
    };

    stage(0, 0);
    stage(1, 32);
    for (int it = 0; it < 32; ++it) {
        int buf = it & 3;
        if (it + 2 < 32) stage((it + 2) & 3, (it + 2) * 32);
        if (it < 30)
            asm volatile("s_waitcnt vmcnt(8)\n\ts_barrier" ::: "memory");
        else if (it == 30)
            asm volatile("s_waitcnt vmcnt(4)\n\ts_barrier" ::: "memory");
        else
            asm volatile("s_waitcnt vmcnt(0)\n\ts_barrier" ::: "memory");
        compute(buf);
    }
    int hi = l >> 4;
#pragma unroll
    for (int m = 0; m < 4; ++m)
#pragma unroll
        for (int c2 = 0; c2 < 4; ++c2) {
            int j = j0 + wc * 64 + c2 * 16 + r;
#pragma unroll
            for (int reg = 0; reg < 4; ++reg) {
                int p = p0 + wr * 64 + m * 16 + hi * 4 + reg;
                Tb[((size_t)n * L + p) * NB + j] = (__bf16)acc[m][c2][reg];
            }
        }
}

// ---- fused gather + oconv + BN stats + BN normalize + residual (single kernel).
// ---- Blocks sync via device atomic flag; grid = 256 = #CUs -> all co-resident. ----
__global__ void k_oconv(const __bf16* __restrict__ owb, const __bf16* __restrict__ Tb,
                        float* __restrict__ stats, const float* __restrict__ gamma,
                        const float* __restrict__ beta, const float* __restrict__ alpha,
                        float* __restrict__ out, unsigned* __restrict__ flags) {
    __shared__ __align__(16) __bf16 As[4 * 4096];  // [chunk][128 j][32]
    __shared__ __align__(16) __bf16 Bp[4 * 2048];  // [chunk][64 pix][32]
    int n = blockIdx.z;
    int x0 = blockIdx.x * 64;
    int t = threadIdx.x, l = t & 63, w = t >> 6;
    int wr = w >> 1, wc = w & 1;
    int gl = l >> 4, r = l & 15, hi = l >> 4;
#pragma unroll
    for (int c = 0; c < 4; ++c)
#pragma unroll
        for (int i = 0; i < 2; ++i) {
            int h = i * 256 + t;          // [0,512): j = h>>2, sgl = h&3
            const __bf16* src = owb + (size_t)(h >> 2) * CH + c * 32 + (h & 3) * 8;
            __builtin_amdgcn_global_load_lds((gbl_t*)src, (lds_t*)(As + c * 4096 + h * 8), 16, 0, 0);
        }
    const __bf16* Tn = Tb + ((size_t)(n * L) << 11);
#pragma unroll
    for (int it = 0; it < 4; ++it) {
        int e2 = it * 256 + t;
        int og = e2 & 15, pl = e2 >> 4;   // pl in [0,64)
        int pix = x0 + pl;
        int x = pix & 63, y = pix >> 6;
        float acc8[8] = {};
        int ap = (y + 1) & 1, bp = (x + 1) & 1;
#pragma unroll
        for (int da = 0; da < 2; ++da) {
            int a = ap + 2 * da;
            int ny = y + 1 - a;
            if (ny < 0 || ny >= 64) continue;
            int py = ny >> 1;
#pragma unroll
            for (int db = 0; db < 2; ++db) {
                int bb = bp + 2 * db;
                int nx = x + 1 - bb;
                if (nx < 0 || nx >= 64) continue;
                int px = nx >> 1;
                bf16x8 v = *(const bf16x8*)(Tn + (((size_t)(py * hh + px)) << 11) + (a * 4 + bb) * 128 + og * 8);
#pragma unroll
                for (int u2 = 0; u2 < 8; ++u2) acc8[u2] += (float)v[u2];
            }
        }
        __bf16 rr[8];
#pragma unroll
        for (int u2 = 0; u2 < 8; ++u2) rr[u2] = (__bf16)(acc8[u2] * 0.25f);
        int key = (pix >> 1) & 3;
        int dgl = (og & 3) ^ key;
        *(bf16x8*)(Bp + (og >> 2) * 2048 + pl * 32 + dgl * 8) = *(bf16x8*)rr;
    }
    __syncthreads();
    f32x4 acc[4][2] = {};
#pragma unroll
    for (int c = 0; c < 4; ++c) {
        bf16x8 av[4], bv[2];
#pragma unroll
        for (int m = 0; m < 4; ++m) {
            int row = wr * 64 + m * 16 + r;
            av[m] = *(const bf16x8*)(As + c * 4096 + row * 32 + ((gl ^ ((row >> 1) & 3)) << 3));
        }
#pragma unroll
        for (int c2 = 0; c2 < 2; ++c2) {
            int col = wc * 32 + c2 * 16 + r;
            bv[c2] = *(const bf16x8*)(Bp + c * 2048 + col * 32 + ((gl ^ ((col >> 1) & 3)) << 3));
        }
#pragma unroll
        for (int m = 0; m < 4; ++m)
#pragma unroll
            for (int c2 = 0; c2 < 2; ++c2)
                acc[m][c2] = __builtin_amdgcn_mfma_f32_16x16x32_bf16(av[m], bv[c2], acc[m][c2], 0, 0, 0);
    }
    __syncthreads();  // done reading As/Bp; reuse As as float scratch
    float* partS = (float*)As;        // [128][2]
    float* partS2 = partS + 256;      // [128][2]
#pragma unroll
    for (int m = 0; m < 4; ++m)
#pragma unroll
        for (int reg = 0; reg < 4; ++reg) {
            float s = 0.f, s2 = 0.f;
#pragma unroll
            for (int c2 = 0; c2 < 2; ++c2) {
                float v = acc[m][c2][reg];
                s += v;
                s2 += v * v;
            }
#pragma unroll
            for (int off = 1; off < 16; off <<= 1) {
                s += __shfl_xor(s, off);
                s2 += __shfl_xor(s2, off);
            }
            if (r == 0) {
                int j = wr * 64 + m * 16 + hi * 4 + reg;
                partS[j * 2 + wc] = s;
                partS2[j * 2 + wc] = s2;
            }
        }
    __syncthreads();
    if (t < 128) {
        atomicAdd(&stats[t * 2], partS[t * 2] + partS[t * 2 + 1]);
        atomicAdd(&stats[t * 2 + 1], partS2[t * 2] + partS2[t * 2 + 1]);
    }
    __syncthreads();  // drains the atomics (vmcnt 0) for all threads
    if (t == 0) {
        __threadfence();            // stats atomics visible before flag bump
        atomicAdd(flags, 1u);
        while (atomicAdd(flags, 0u) < 256u) __builtin_amdgcn_s_sleep(1);
    }
    __syncthreads();
    // finalize BN params into LDS (coherent reads via atomic returns)
    float* mu_s = (float*)Bp;         // [128]
    float* ivg_s = mu_s + 128;        // inv * gamma
    float* bt_s = mu_s + 256;         // beta
    if (t < 128) {
        float s1 = atomicAdd(&stats[t * 2], 0.0f);
        float s2 = atomicAdd(&stats[t * 2 + 1], 0.0f);
        float mu = s1 * (1.0f / 16384.0f);
        float var = s2 * (1.0f / 16384.0f) - mu * mu;
        mu_s[t] = mu;
        ivg_s[t] = rsqrtf(var + 1e-5f) * gamma[t];
        bt_s[t] = beta[t];
    }
    __syncthreads();
#pragma unroll
    for (int m = 0; m < 4; ++m)
#pragma unroll
        for (int c2 = 0; c2 < 2; ++c2) {
            int pix = x0 + wc * 32 + c2 * 16 + r;
#pragma unroll
            for (int reg = 0; reg < 4; ++reg) {
                int j = wr * 64 + m * 16 + hi * 4 + reg;
                size_t off = (((size_t)n * CH + j) << 12) + pix;
                out[off] = (acc[m][c2][reg] - mu_s[j]) * ivg_s[j] + bt_s[j] + alpha[off];
            }
        }
}

extern "C" void kernel_launch(void* const* d_in, const int* in_sizes, int n_in,
                              void* d_out, int out_size, void* d_ws, size_t ws_size,
                              hipStream_t stream) {
    const float* img = (const float*)d_in[0];
    const float* alpha = (const float*)d_in[1];
    const float* unknown = (const float*)d_in[2];
    const float* gw = (const float*)d_in[3];
    const float* gb = (const float*)d_in[4];
    const float* ow = (const float*)d_in[5];
    const float* gamma = (const float*)d_in[6];
    const float* beta = (const float*)d_in[7];
    float* out = (float*)d_out;
    float* ws = (float*)d_ws;

    // layout (float-word offsets)
    __bf16* Xb = (__bf16*)(ws);                // 524288 fw
    __bf16* gwb = (__bf16*)(ws + 524288);      // 16384 fw
    __bf16* owb = (__bf16*)(ws + 540672);      // 8192 fw
    __bf16* gbf = (__bf16*)(ws + 548864);      // 262144 fw  (4096x128 bf16)
    float* unk = ws + 815104;                  // 4096
    float* scales = ws + 819200;               // 64 (flags at [56])
    float* stats = ws + 819264;                // 256
    float* W = ws + 819520;                    // 4194304 fw
    __bf16* Wb = (__bf16*)(ws + 5013824);      // 2097152 fw
    __bf16* Bt = (__bf16*)(ws + 7110976);      // 4194304 fw
    __bf16* Tb = (__bf16*)(ws + 11305280);     // 4194304 fw
    unsigned* flags = (unsigned*)(ws + 819256);

    k_prep<<<680, 256, 0, stream>>>(img, gw, ow, unknown, alpha, Xb, gwb, owb, unk, scales, Bt, stats);
    k_gemm0<<<32, 256, 0, stream>>>(Xb, gwb, gb, gbf);
    k_gemm1<<<dim3(8, 8, 4), 256, 0, stream>>>(gbf, unk, scales, W);
    k_softmax<<<1024, 256, 0, stream>>>(W, Wb);
    k_gemm2<<<512, 256, 0, stream>>>(Wb, Bt, Tb);
    k_oconv<<<dim3(64, 1, 4), 256, 0, stream>>>(owb, Tb, stats, gamma, beta, alpha, out, flags);
}

// Round 7
// 91.264 us; speedup vs baseline: 1.1864x; 1.1864x over previous
//
#include <hip/hip_runtime.h>

#define NN 4
#define CIN 256
#define CH 128       // gconv out channels = AC = oconv channels
#define HH 64
#define hh 32
#define L 1024
#define NB 2048      // CH*16
#define PENALTY -10000.0f
#define EPS 1e-4f

typedef __bf16 bf16x8 __attribute__((ext_vector_type(8)));
typedef float f32x4 __attribute__((ext_vector_type(4)));
typedef __attribute__((address_space(3))) void lds_t;
typedef __attribute__((address_space(1))) const void gbl_t;

__device__ __forceinline__ int refl32(int t) { return t < 0 ? -t : (t > 31 ? 62 - t : t); }
__device__ __forceinline__ int refl64(int t) { return t < 0 ? -t : (t > 63 ? 126 - t : t); }
// XOR-swizzle of element index (16B/8-elem granule) within a 32-elem K-chunk, keyed by row
__device__ __forceinline__ int swz(int k, int row) { return k ^ (((row >> 1) & 3) << 3); }

// ---- prep: img downsample+transpose (blocks 0..127), unknown stats (128..131),
// ---- weight convert + stats-zero (132..167). btbuild moved to k_gemm1 co-launch. ----
__global__ void k_prep(const float* __restrict__ img, const float* __restrict__ gw,
                       const float* __restrict__ ow, const float* __restrict__ unknown,
                       __bf16* __restrict__ Xb, __bf16* __restrict__ gwb,
                       __bf16* __restrict__ owb, float* __restrict__ unk,
                       float* __restrict__ scales, float* __restrict__ stats) {
    __shared__ float sm[CIN * 33];
    int bid = blockIdx.x, t = threadIdx.x;
    if (bid < 128) {
        // prep_x: downsample img (float4 -> keep .x/.z), transpose to [np][c], bf16
        int i = bid & 31, n = bid >> 5;
        for (int e = t; e < CIN * 16; e += 256) {
            int c = e >> 4, j2 = e & 15;
            float4 v = *(const float4*)(img + (((size_t)n * CIN + c) * HH + 2 * i) * HH + 4 * j2);
            sm[c * 33 + 2 * j2] = v.x;
            sm[c * 33 + 2 * j2 + 1] = v.z;
        }
        __syncthreads();
#pragma unroll
        for (int j = 0; j < 32; ++j) {
            int np = (n << 10) + i * 32 + j;
            int cl = swz(t, np);
            Xb[(size_t)np * CIN + t] = (__bf16)sm[cl * 33 + j];
        }
    } else if (bid < 132) {
        // stats: unknown downsample, mean -> scales, 3x3 reflect box mean -> unk
        int n = bid - 128;
        float* u = sm;            // [1024]
        float* red = sm + 1024;   // [256]
        float part = 0.f;
#pragma unroll
        for (int c = 0; c < 4; ++c) {
            int idx = t + c * 256;
            int i = idx >> 5, j = idx & 31;
            float v = unknown[n * 4096 + (2 * i) * HH + 2 * j];
            u[idx] = v;
            part += v;
        }
        red[t] = part;
        __syncthreads();
        for (int s = 128; s > 0; s >>= 1) {
            if (t < s) red[t] += red[t + s];
            __syncthreads();
        }
        if (t == 0) {
            float um = red[0] / 1024.0f;
            float km = 1.0f - um;
            scales[n * 2] = fminf(fmaxf(sqrtf(um / km), 0.1f), 10.0f);
            scales[n * 2 + 1] = fminf(fmaxf(sqrtf(km / um), 0.1f), 10.0f);
        }
#pragma unroll
        for (int c = 0; c < 4; ++c) {
            int idx = t + c * 256;
            int i = idx >> 5, j = idx & 31;
            float sum = 0.f;
#pragma unroll
            for (int di = -1; di <= 1; ++di)
#pragma unroll
                for (int dj = -1; dj <= 1; ++dj)
                    sum += u[refl32(i + di) * 32 + refl32(j + dj)];
            unk[n * L + idx] = sum * (1.0f / 9.0f);
        }
    } else {
        // prep_w: weights -> bf16 pre-swizzled; block 132 zeros BN stats accumulator
        if (bid == 132) stats[t] = 0.f;
        for (int e = (bid - 132) * 256 + t; e < 49152; e += 36 * 256) {
            if (e < 32768) {
                int o = e >> 8, m = e & 255;
                gwb[e] = (__bf16)gw[o * 256 + swz(m, o)];
            } else {
                int e2 = e - 32768;
                int j = e2 >> 7, m = e2 & 127;
                owb[e2] = (__bf16)ow[j * 128 + swz(m, j)];
            }
        }
    }
}

// ---- MFMA GEMM0: gbf[np][o] = Xb . gwb^T + gb, bf16 out ----
__global__ __launch_bounds__(256, 2) void k_gemm0(const __bf16* __restrict__ Xb,
                                                  const __bf16* __restrict__ gwb,
                                                  const float* __restrict__ gb,
                                                  __bf16* __restrict__ gbf) {
    __shared__ __align__(16) __bf16 As[128 * 32];
    __shared__ __align__(16) __bf16 Bs[128 * 32];
    int p0 = blockIdx.x * 128;
    int t = threadIdx.x, l = t & 63, w = t >> 6;
    int wr = w >> 1, wc = w & 1;
    f32x4 acc[4][4] = {};
    for (int k0 = 0; k0 < CIN; k0 += 32) {
#pragma unroll
        for (int i = 0; i < 2; ++i) {
            const __bf16* srcA = Xb + (size_t)(p0 + i * 64 + (t >> 2)) * CIN + k0 + (t & 3) * 8;
            __builtin_amdgcn_global_load_lds((gbl_t*)srcA, (lds_t*)(As + i * 2048 + t * 8), 16, 0, 0);
            const __bf16* srcB = gwb + (size_t)(i * 64 + (t >> 2)) * CIN + k0 + (t & 3) * 8;
            __builtin_amdgcn_global_load_lds((gbl_t*)srcB, (lds_t*)(Bs + i * 2048 + t * 8), 16, 0, 0);
        }
        __syncthreads();
        int gl = l >> 4, r = l & 15;
        bf16x8 av[4], bv[4];
#pragma unroll
        for (int m = 0; m < 4; ++m) {
            int row = wr * 64 + m * 16 + r;
            av[m] = *(const bf16x8*)(As + row * 32 + swz(gl << 3, row));
            int col = wc * 64 + m * 16 + r;
            bv[m] = *(const bf16x8*)(Bs + col * 32 + swz(gl << 3, col));
        }
#pragma unroll
        for (int m = 0; m < 4; ++m)
#pragma unroll
            for (int c2 = 0; c2 < 4; ++c2)
                acc[m][c2] = __builtin_amdgcn_mfma_f32_16x16x32_bf16(av[m], bv[c2], acc[m][c2], 0, 0, 0);
        __syncthreads();
    }
    int r = l & 15, hi = l >> 4;
#pragma unroll
    for (int m = 0; m < 4; ++m)
#pragma unroll
        for (int c2 = 0; c2 < 4; ++c2) {
            int o = wc * 64 + c2 * 16 + r;
            float bias = gb[o];
#pragma unroll
            for (int reg = 0; reg < 4; ++reg) {
                int row = p0 + wr * 64 + m * 16 + hi * 4 + reg;
                gbf[((size_t)row << 7) + o] = (__bf16)(acc[m][c2][reg] + bias);
            }
        }
}

// ---- MFMA GEMM1 + fused ssq/normf (blocks 0..255) co-launched with btbuild
// ---- (blocks 256..767, alpha->Bt, pure BW — overlaps gemm1's compute). ----
__global__ __launch_bounds__(256, 2) void k_gemm1(const __bf16* __restrict__ gbf,
                                                  const float* __restrict__ unk,
                                                  const float* __restrict__ scales,
                                                  const float* __restrict__ alpha,
                                                  float* __restrict__ W,
                                                  __bf16* __restrict__ Bt) {
    __shared__ __align__(16) unsigned char RAW[75008];
    int bid = blockIdx.x, t = threadIdx.x;
    if (bid >= 256) {
        // btbuild: one block per (n,o): stage alpha plane (coalesced), emit 16 ab rows.
        float* sm = (float*)RAW;  // [64][65]
        int blk = bid - 256;
        int n = blk >> 7, o = blk & 127;
        const float* ap = alpha + ((size_t)(n * CH + o) << 12);
#pragma unroll
        for (int j = 0; j < 4; ++j) {
            int fi = t + j * 256;      // float4 index 0..1023
            int row = fi >> 4, c4 = fi & 15;
            float4 v = *(const float4*)(ap + fi * 4);
            float* d = sm + row * 65 + c4 * 4;
            d[0] = v.x; d[1] = v.y; d[2] = v.z; d[3] = v.w;
        }
        __syncthreads();
        __bf16* Bn = Bt + ((size_t)(n * NB) << 10);
#pragma unroll
        for (int gi = 0; gi < 8; ++gi) {
            int g = gi * 256 + t;      // granule 0..2047
            int ab = g >> 7, qg = g & 127;
            int a = ab >> 2, bb = ab & 3;
            int q0 = qg * 8;
            int qi = q0 >> 5, qj0 = q0 & 31;
            int ti = refl64(2 * qi + a - 1);
            const float* r = sm + ti * 65;
            __bf16 v[8];
#pragma unroll
            for (int s = 0; s < 8; ++s) v[s] = (__bf16)r[refl64(2 * (qj0 + s) + bb - 1)];
            int j = ab * 128 + o;
            *(bf16x8*)(Bn + ((size_t)j << 10) + swz(q0, j)) = *(bf16x8*)v;
        }
        return;
    }
    __bf16* As1 = (__bf16*)RAW;            // [4][192][32]
    __bf16* Bh = (__bf16*)(RAW + 49152);   // [2][192][32]
    float* ssq = (float*)(RAW + 73728);    // [192]
    float* ftile = ssq + 192;              // [128]
    int n = bid >> 6;
    int yy = (bid >> 3) & 7, xx = bid & 7;
    int p0 = yy * 128, q0 = xx * 128;
    const __bf16* gn = gbf + ((size_t)n << 17);
    int l = t & 63, w = t >> 6;
    int wr = w >> 1, wc = w & 1;
    int by4 = yy * 4, bx4 = xx * 4;
    int rbA = by4 - 1; rbA = rbA < 0 ? 0 : (rbA > 26 ? 26 : rbA);
    int rbB = bx4 - 1; rbB = rbB < 0 ? 0 : (rbB > 26 ? 26 : rbB);
#pragma unroll
    for (int k = 0; k < 12; ++k) {  // stage full A window
        int chunk = k / 3;
        int rem = (k % 3) * 256 + t;
        int wrow = rem >> 2, sg = rem & 3;
        int so = (chunk << 5) + ((sg ^ ((wrow >> 1) & 3)) << 3);
        int grA = ((rbA + (wrow >> 5)) << 5) + (wrow & 31);
        __builtin_amdgcn_global_load_lds((gbl_t*)(gn + (size_t)grA * 128 + so),
                                         (lds_t*)(As1 + chunk * 6144 + rem * 8), 16, 0, 0);
    }
    auto stageB = [&](int h) {
#pragma unroll
        for (int k = 0; k < 6; ++k) {
            int cl = k / 3;
            int cc = 2 * h + cl;
            int rem = (k % 3) * 256 + t;
            int wrow = rem >> 2, sg = rem & 3;
            int so = (cc << 5) + ((sg ^ ((wrow >> 1) & 3)) << 3);
            int grB = ((rbB + (wrow >> 5)) << 5) + (wrow & 31);
            __builtin_amdgcn_global_load_lds((gbl_t*)(gn + (size_t)grB * 128 + so),
                                             (lds_t*)(Bh + cl * 6144 + rem * 8), 16, 0, 0);
        }
    };
    stageB(0);
    int gl = l >> 4, r = l & 15;
    int rpA_[4][3], cpA_[4][3], rpB_[4][3], cpB_[4][3];
#pragma unroll
    for (int m = 0; m < 4; ++m) {
        int prow = wr * 64 + m * 16 + r;
        int qrow = wc * 64 + m * 16 + r;
#pragma unroll
        for (int d = 0; d < 3; ++d) {
            rpA_[m][d] = (refl32(by4 + (prow >> 5) + d - 1) - rbA) << 10;
            int cp = refl32((prow & 31) + d - 1);
            cpA_[m][d] = cp * 32 + ((gl ^ ((cp >> 1) & 3)) << 3);
            rpB_[m][d] = (refl32(bx4 + (qrow >> 5) + d - 1) - rbB) << 10;
            int cq = refl32((qrow & 31) + d - 1);
            cpB_[m][d] = cq * 32 + ((gl ^ ((cq >> 1) & 3)) << 3);
        }
    }
    f32x4 acc[4][4] = {};
    float ssqAcc = 0.f;
    auto computeH = [&](int h) {
        __builtin_amdgcn_s_setprio(1);
#pragma unroll
        for (int dk = 0; dk < 3; ++dk)
#pragma unroll
            for (int dl = 0; dl < 3; ++dl)
#pragma unroll
                for (int c = 0; c < 2; ++c) {
                    int cc = 2 * h + c;
                    bf16x8 av[4], bv[4];
#pragma unroll
                    for (int m = 0; m < 4; ++m) {
                        av[m] = *(const bf16x8*)(As1 + cc * 6144 + rpA_[m][dk] + cpA_[m][dl]);
                        bv[m] = *(const bf16x8*)(Bh + c * 6144 + rpB_[m][dk] + cpB_[m][dl]);
                    }
#pragma unroll
                    for (int m = 0; m < 4; ++m)
#pragma unroll
                        for (int c2 = 0; c2 < 4; ++c2)
                            acc[m][c2] = __builtin_amdgcn_mfma_f32_16x16x32_bf16(av[m], bv[c2], acc[m][c2], 0, 0, 0);
                }
        __builtin_amdgcn_s_setprio(0);
        // ssq partial from this B half (ch [h*64, h*64+64) in linear order)
        if (t < 192) {
            int key = (t >> 1) & 3;
#pragma unroll
            for (int c = 0; c < 2; ++c)
#pragma unroll
                for (int g = 0; g < 4; ++g) {
                    bf16x8 v = *(const bf16x8*)(Bh + c * 6144 + t * 32 + ((g ^ key) << 3));
#pragma unroll
                    for (int u2 = 0; u2 < 8; ++u2) {
                        float x = (float)v[u2];
                        ssqAcc += x * x;
                    }
                }
        }
    };
    __syncthreads();
    computeH(0);
    __syncthreads();
    stageB(1);
    __syncthreads();
    computeH(1);
    if (t < 192) ssq[t] = ssqAcc;
    __syncthreads();
    if (t < 128) {
        int q = q0 + t;
        int qi = q >> 5, qj = q & 31;
        float sum = 0.f;
#pragma unroll
        for (int di = -1; di <= 1; ++di)
#pragma unroll
            for (int dj = -1; dj <= 1; ++dj)
                sum += ssq[(refl32(qi + di) - rbB) * 32 + refl32(qj + dj)];
        float sc = unk[n * L + q] > 0.f ? scales[n * 2] : scales[n * 2 + 1];
        ftile[t] = sc / fmaxf(sqrtf(sum), EPS);
    }
    __syncthreads();
    int hi = l >> 4;
#pragma unroll
    for (int m = 0; m < 4; ++m)
#pragma unroll
        for (int c2 = 0; c2 < 4; ++c2) {
            int q = q0 + wc * 64 + c2 * 16 + r;
            float fq = ftile[wc * 64 + c2 * 16 + r];
#pragma unroll
            for (int reg = 0; reg < 4; ++reg) {
                int p = p0 + wr * 64 + m * 16 + hi * 4 + reg;
                float val = acc[m][c2][reg] * fq;
                if (p == q) val += PENALTY * unk[n * L + p];
                W[((size_t)n << 20) + ((size_t)p << 10) + q] = val;
            }
        }
}

// ---- row softmax: one wave per row, shuffle-only; writes swizzled bf16 Wb ----
__global__ void k_softmax(const float* __restrict__ W, __bf16* __restrict__ Wb) {
    int t = threadIdx.x, wv = t >> 6, lane = t & 63;
    int row = blockIdx.x * 4 + wv;  // n*L + p
    const float* Wr = W + (size_t)row * 1024;
    float v[16];
    float mx = -1e30f;
#pragma unroll
    for (int k = 0; k < 16; ++k) {
        v[k] = Wr[lane + k * 64];
        mx = fmaxf(mx, v[k]);
    }
#pragma unroll
    for (int off = 32; off > 0; off >>= 1) mx = fmaxf(mx, __shfl_xor(mx, off));
    float sum = 0.f;
#pragma unroll
    for (int k = 0; k < 16; ++k) {
        v[k] = __expf(v[k] - mx);
        sum += v[k];
    }
#pragma unroll
    for (int off = 32; off > 0; off >>= 1) sum += __shfl_xor(sum, off);
    float inv = 1.0f / sum;
    int p = row & (L - 1);
    int key = ((p >> 1) & 3) << 3;
    __bf16* Wbr = Wb + (size_t)row * 1024;
#pragma unroll
    for (int k = 0; k < 16; ++k) {
        int idx = lane + k * 64;
        Wbr[idx ^ key] = (__bf16)(v[k] * inv);
    }
}

// ---- MFMA GEMM2: Tb[p][j] = sum_q W[p][q] * Bt[j][q].
// ---- 4-buffer BK=32 pipeline, counted vmcnt (T4): never drain to 0 mid-loop. ----
__global__ __launch_bounds__(256, 2) void k_gemm2(const __bf16* __restrict__ Wb,
                                                  const __bf16* __restrict__ Bt,
                                                  __bf16* __restrict__ Tb) {
    int bid = blockIdx.x;
    int xcd = bid & 7, idx = bid >> 3;
    int n = xcd >> 1;
    int p0 = ((xcd & 1) * 4 + (idx & 3)) * 128;
    int j0 = (idx >> 2) * 128;
    __shared__ __align__(16) __bf16 As[4][4096];  // [buf][128 rows][32]
    __shared__ __align__(16) __bf16 Bs[4][4096];
    const __bf16* An = Wb + ((size_t)n << 20);
    const __bf16* Bn = Bt + ((size_t)n * NB << 10);
    int t = threadIdx.x, l = t & 63, w = t >> 6;
    int wr = w >> 1, wc = w & 1;
    int gl = l >> 4, r = l & 15;
    f32x4 acc[4][4] = {};

    auto stage = [&](int buf, int k0) {
#pragma unroll
        for (int i = 0; i < 2; ++i) {
            int row = (t >> 2) + i * 64;
            int sgo = (t & 3) * 8;
            const __bf16* srcA = An + ((size_t)(p0 + row) << 10) + k0 + sgo;
            __builtin_amdgcn_global_load_lds((gbl_t*)srcA, (lds_t*)(&As[buf][row * 32 + sgo]), 16, 0, 0);
            const __bf16* srcB = Bn + ((size_t)(j0 + row) << 10) + k0 + sgo;
            __builtin_amdgcn_global_load_lds((gbl_t*)srcB, (lds_t*)(&Bs[buf][row * 32 + sgo]), 16, 0, 0);
        }
    };
    auto compute = [&](int buf) {
        bf16x8 av[4], bv[4];
#pragma unroll
        for (int m = 0; m < 4; ++m) {
            int row = wr * 64 + m * 16 + r;
            av[m] = *(const bf16x8*)(&As[buf][row * 32 + ((gl ^ ((row >> 1) & 3)) << 3)]);
            int col = wc * 64 + m * 16 + r;
            bv[m] = *(const bf16x8*)(&Bs[buf][col * 32 + ((gl ^ ((col >> 1) & 3)) << 3)]);
        }
#pragma unroll
        for (int m = 0; m < 4; ++m)
#pragma unroll
            for (int c2 = 0; c2 < 4; ++c2)
                acc[m][c2] = __builtin_amdgcn_mfma_f32_16x16x32_bf16(av[m], bv[c2], acc[m][c2], 0, 0, 0);
    };

    stage(0, 0);
    stage(1, 32);
    for (int it = 0; it < 32; ++it) {
        int buf = it & 3;
        if (it + 2 < 32) stage((it + 2) & 3, (it + 2) * 32);
        if (it < 30)
            asm volatile("s_waitcnt vmcnt(8)\n\ts_barrier" ::: "memory");
        else if (it == 30)
            asm volatile("s_waitcnt vmcnt(4)\n\ts_barrier" ::: "memory");
        else
            asm volatile("s_waitcnt vmcnt(0)\n\ts_barrier" ::: "memory");
        compute(buf);
    }
    int hi = l >> 4;
#pragma unroll
    for (int m = 0; m < 4; ++m)
#pragma unroll
        for (int c2 = 0; c2 < 4; ++c2) {
            int j = j0 + wc * 64 + c2 * 16 + r;
#pragma unroll
            for (int reg = 0; reg < 4; ++reg) {
                int p = p0 + wr * 64 + m * 16 + hi * 4 + reg;
                Tb[((size_t)n * L + p) * NB + j] = (__bf16)acc[m][c2][reg];
            }
        }
}

// ---- fused gather + oconv + BN partials ----
__global__ void k_oconv(const __bf16* __restrict__ owb, const __bf16* __restrict__ Tb,
                        float* __restrict__ y2, float* __restrict__ stats) {
    __shared__ __align__(16) __bf16 As[4 * 4096];  // [chunk][128 j][32]
    __shared__ __align__(16) __bf16 Bp[4 * 2048];  // [chunk][64 pix][32]
    int n = blockIdx.z;
    int x0 = blockIdx.x * 64;
    int t = threadIdx.x, l = t & 63, w = t >> 6;
    int wr = w >> 1, wc = w & 1;
    int gl = l >> 4, r = l & 15, hi = l >> 4;
#pragma unroll
    for (int c = 0; c < 4; ++c)
#pragma unroll
        for (int i = 0; i < 2; ++i) {
            int h = i * 256 + t;          // [0,512): j = h>>2, sgl = h&3
            const __bf16* src = owb + (size_t)(h >> 2) * CH + c * 32 + (h & 3) * 8;
            __builtin_amdgcn_global_load_lds((gbl_t*)src, (lds_t*)(As + c * 4096 + h * 8), 16, 0, 0);
        }
    const __bf16* Tn = Tb + ((size_t)(n * L) << 11);
#pragma unroll
    for (int it = 0; it < 4; ++it) {
        int e2 = it * 256 + t;
        int og = e2 & 15, pl = e2 >> 4;   // pl in [0,64)
        int pix = x0 + pl;
        int x = pix & 63, y = pix >> 6;
        float acc8[8] = {};
        int ap = (y + 1) & 1, bp = (x + 1) & 1;
#pragma unroll
        for (int da = 0; da < 2; ++da) {
            int a = ap + 2 * da;
            int ny = y + 1 - a;
            if (ny < 0 || ny >= 64) continue;
            int py = ny >> 1;
#pragma unroll
            for (int db = 0; db < 2; ++db) {
                int bb = bp + 2 * db;
                int nx = x + 1 - bb;
                if (nx < 0 || nx >= 64) continue;
                int px = nx >> 1;
                bf16x8 v = *(const bf16x8*)(Tn + (((size_t)(py * hh + px)) << 11) + (a * 4 + bb) * 128 + og * 8);
#pragma unroll
                for (int u2 = 0; u2 < 8; ++u2) acc8[u2] += (float)v[u2];
            }
        }
        __bf16 rr[8];
#pragma unroll
        for (int u2 = 0; u2 < 8; ++u2) rr[u2] = (__bf16)(acc8[u2] * 0.25f);
        int key = (pix >> 1) & 3;
        int dgl = (og & 3) ^ key;
        *(bf16x8*)(Bp + (og >> 2) * 2048 + pl * 32 + dgl * 8) = *(bf16x8*)rr;
    }
    __syncthreads();
    f32x4 acc[4][2] = {};
#pragma unroll
    for (int c = 0; c < 4; ++c) {
        bf16x8 av[4], bv[2];
#pragma unroll
        for (int m = 0; m < 4; ++m) {
            int row = wr * 64 + m * 16 + r;
            av[m] = *(const bf16x8*)(As + c * 4096 + row * 32 + ((gl ^ ((row >> 1) & 3)) << 3));
        }
#pragma unroll
        for (int c2 = 0; c2 < 2; ++c2) {
            int col = wc * 32 + c2 * 16 + r;
            bv[c2] = *(const bf16x8*)(Bp + c * 2048 + col * 32 + ((gl ^ ((col >> 1) & 3)) << 3));
        }
#pragma unroll
        for (int m = 0; m < 4; ++m)
#pragma unroll
            for (int c2 = 0; c2 < 2; ++c2)
                acc[m][c2] = __builtin_amdgcn_mfma_f32_16x16x32_bf16(av[m], bv[c2], acc[m][c2], 0, 0, 0);
    }
#pragma unroll
    for (int m = 0; m < 4; ++m)
#pragma unroll
        for (int c2 = 0; c2 < 2; ++c2) {
            int pix = x0 + wc * 32 + c2 * 16 + r;
#pragma unroll
            for (int reg = 0; reg < 4; ++reg) {
                int j = wr * 64 + m * 16 + hi * 4 + reg;
                y2[(((size_t)n * CH + j) << 12) + pix] = acc[m][c2][reg];
            }
        }
    __syncthreads();  // done reading As/Bp; reuse As as float scratch
    float* partS = (float*)As;        // [128][2]
    float* partS2 = partS + 256;      // [128][2]
#pragma unroll
    for (int m = 0; m < 4; ++m)
#pragma unroll
        for (int reg = 0; reg < 4; ++reg) {
            float s = 0.f, s2 = 0.f;
#pragma unroll
            for (int c2 = 0; c2 < 2; ++c2) {
                float v = acc[m][c2][reg];
                s += v;
                s2 += v * v;
            }
#pragma unroll
            for (int off = 1; off < 16; off <<= 1) {
                s += __shfl_xor(s, off);
                s2 += __shfl_xor(s2, off);
            }
            if (r == 0) {
                int j = wr * 64 + m * 16 + hi * 4 + reg;
                partS[j * 2 + wc] = s;
                partS2[j * 2 + wc] = s2;
            }
        }
    __syncthreads();
    if (t < 128) {
        atomicAdd(&stats[t * 2], partS[t * 2] + partS[t * 2 + 1]);
        atomicAdd(&stats[t * 2 + 1], partS2[t * 2] + partS2[t * 2 + 1]);
    }
}

// ---- BN normalize + residual (float4) ----
__global__ void k_final(const float* __restrict__ y2, const float* __restrict__ stats,
                        const float* __restrict__ gamma, const float* __restrict__ beta,
                        const float* __restrict__ alpha, float* __restrict__ out) {
    int e4 = blockIdx.x * 256 + threadIdx.x;  // < 524288 float4s
    int oc = (e4 >> 10) & 127;
    float s1 = stats[oc * 2], s2 = stats[oc * 2 + 1];
    float mu = s1 * (1.0f / 16384.0f);
    float var = s2 * (1.0f / 16384.0f) - mu * mu;
    float inv = rsqrtf(var + 1e-5f);
    float g = gamma[oc], b = beta[oc];
    float4 yv = ((const float4*)y2)[e4];
    float4 av = ((const float4*)alpha)[e4];
    float4 o;
    o.x = (yv.x - mu) * inv * g + b + av.x;
    o.y = (yv.y - mu) * inv * g + b + av.y;
    o.z = (yv.z - mu) * inv * g + b + av.z;
    o.w = (yv.w - mu) * inv * g + b + av.w;
    ((float4*)out)[e4] = o;
}

extern "C" void kernel_launch(void* const* d_in, const int* in_sizes, int n_in,
                              void* d_out, int out_size, void* d_ws, size_t ws_size,
                              hipStream_t stream) {
    const float* img = (const float*)d_in[0];
    const float* alpha = (const float*)d_in[1];
    const float* unknown = (const float*)d_in[2];
    const float* gw = (const float*)d_in[3];
    const float* gb = (const float*)d_in[4];
    const float* ow = (const float*)d_in[5];
    const float* gamma = (const float*)d_in[6];
    const float* beta = (const float*)d_in[7];
    float* out = (float*)d_out;
    float* ws = (float*)d_ws;

    // layout (float-word offsets)
    __bf16* Xb = (__bf16*)(ws);                // 524288 fw
    __bf16* gwb = (__bf16*)(ws + 524288);      // 16384 fw
    __bf16* owb = (__bf16*)(ws + 540672);      // 8192 fw
    __bf16* gbf = (__bf16*)(ws + 548864);      // 262144 fw  (4096x128 bf16)
    float* unk = ws + 815104;                  // 4096
    float* scales = ws + 819200;               // 64
    float* stats = ws + 819264;                // 256
    float* W = ws + 819520;                    // 4194304 fw
    __bf16* Wb = (__bf16*)(ws + 5013824);      // 2097152 fw
    __bf16* Bt = (__bf16*)(ws + 7110976);      // 4194304 fw
    __bf16* Tb = (__bf16*)(ws + 11305280);     // 4194304 fw
    float* y2 = ws + 15499584;                 // 2097152 fw

    k_prep<<<168, 256, 0, stream>>>(img, gw, ow, unknown, Xb, gwb, owb, unk, scales, stats);
    k_gemm0<<<32, 256, 0, stream>>>(Xb, gwb, gb, gbf);
    k_gemm1<<<768, 256, 0, stream>>>(gbf, unk, scales, alpha, W, Bt);
    k_softmax<<<1024, 256, 0, stream>>>(W, Wb);
    k_gemm2<<<512, 256, 0, stream>>>(Wb, Bt, Tb);
    k_oconv<<<dim3(64, 1, 4), 256, 0, stream>>>(owb, Tb, y2, stats);
    k_final<<<2048, 256, 0, stream>>>(y2, stats, gamma, beta, alpha, out);
}